// Round 2
// baseline (25972.610 us; speedup 1.0000x reference)
//
#include <hip/hip_runtime.h>
#include <stdint.h>

typedef __bf16 bf8 __attribute__((ext_vector_type(8)));
typedef float  f4  __attribute__((ext_vector_type(4)));

__device__ __forceinline__ float b2f(unsigned short u){
  union { float f; unsigned int u; } v; v.u = ((unsigned int)u) << 16; return v.f;
}
__device__ __forceinline__ unsigned short f2b(float f){
  union { float f; unsigned int u; } v; v.f = f;
  unsigned int x = v.u;
  if ((x & 0x7fffffffu) > 0x7f800000u) return (unsigned short)0x7fc0; // NaN
  return (unsigned short)((x + 0x7fffu + ((x >> 16) & 1u)) >> 16);
}

// ---- weight pre-transpose: W [nmat][256][256] fp32 (k,n) -> Wt [nmat][n=256][k=256] bf16
__global__ void k_transpose256(const float* __restrict__ W, unsigned short* __restrict__ Wt, int total){
  int i = blockIdx.x*256 + threadIdx.x;
  if (i >= total) return;
  int mat = i >> 16;
  int r = i & 0xffff;
  int k = r >> 8, n = r & 255;
  Wt[(mat << 16) | (n << 8) | k] = f2b(W[i]);
}
// W_out [256][128] fp32 -> Wt [128][256] bf16
__global__ void k_transpose_out(const float* __restrict__ W, unsigned short* __restrict__ Wt){
  int i = blockIdx.x*256 + threadIdx.x;
  if (i >= 32768) return;
  int k = i >> 7, n = i & 127;
  Wt[n*256 + k] = f2b(W[i]);
}

// ---- embedding gather + cvt to bf16 (2 elems/thread)
__global__ void k_gather2(const float* __restrict__ tab, const int* __restrict__ idx,
                          unsigned short* __restrict__ x, int n){
  int i = blockIdx.x*256 + threadIdx.x;
  if (i >= n*128) return;
  int row = i >> 7, c2 = i & 127;
  const float* p = tab + (long)idx[row]*256 + c2*2;
  float2 v = *(const float2*)p;
  ushort2 o; o.x = f2b(v.x); o.y = f2b(v.y);
  *(ushort2*)(x + (long)row*256 + c2*2) = o;
}

__global__ void k_deg(const int* __restrict__ dst, int E, float* __restrict__ deg){
  int e = blockIdx.x*256 + threadIdx.x;
  if (e < E) atomicAdd(deg + dst[e], 1.0f);
}
__global__ void k_recip(float* __restrict__ p, int n){
  int i = blockIdx.x*256 + threadIdx.x;
  if (i < n) p[i] = 1.0f / fmaxf(p[i], 1.0f);
}

// ---- scatter-add: one wave per edge, lane covers 4 columns
__global__ void k_scatter(const unsigned short* __restrict__ x, const int* __restrict__ esrc,
                          const int* __restrict__ edst, int E, float* __restrict__ agg){
  int wid = (blockIdx.x*256 + threadIdx.x) >> 6;
  if (wid >= E) return;
  int lane = threadIdx.x & 63;
  int s = esrc[wid], d = edst[wid];
  ushort4 v = *(const ushort4*)(x + (long)s*256 + lane*4);
  float* a = agg + (long)d*256 + lane*4;
  atomicAdd(a+0, b2f(v.x));
  atomicAdd(a+1, b2f(v.y));
  atomicAdd(a+2, b2f(v.z));
  atomicAdd(a+3, b2f(v.w));
}

// ---- mean = agg * invdeg, cvt to bf16 (2 elems/thread)
__global__ void k_meancvt2(const float* __restrict__ agg, const float* __restrict__ invdeg,
                           unsigned short* __restrict__ mean, int n){
  int i = blockIdx.x*256 + threadIdx.x;
  if (i >= n*128) return;
  int row = i >> 7;
  float2 v = *(const float2*)(agg + (long)i*2);
  float s = invdeg[row];
  ushort2 o; o.x = f2b(v.x*s); o.y = f2b(v.y*s);
  *(ushort2*)(mean + (long)i*2) = o;
}

// ---- fused multi-type SAGE layer kernel
// For destination d with types T: x_d_new = relu( sum_t normalize(mean_t@Wl_t + x_d@Wr_t + b_t) )
// block = 4 waves; tile 64 rows x 256 cols (full H); wave w -> cols [64w, 64w+64)
// In-place: out == xd is safe (each block reads only its own 64 rows of xd).
struct SagePart {
  const void* A;                 // [N][256] fp32 agg (invdeg!=null) or bf16 mean (invdeg==null)
  const unsigned short* Wl;      // [n=256][k=256] bf16
  const unsigned short* Wr;      // [n=256][k=256] bf16
  const float* bias;             // [256] fp32
  const float* invdeg;           // [N] fp32 or null
};
struct SageArgs {
  SagePart p[3];
  const unsigned short* xd;      // [N][256] bf16
  unsigned short* out;           // [N][256] bf16 (may alias xd)
  int N;
  int ntypes;
};

__global__ __launch_bounds__(256) void k_sage(SageArgs args)
{
  __shared__ float ssq[64];
  const int tid = threadIdx.x;
  const int wave = tid >> 6, lane = tid & 63;
  const int q = lane >> 4, m = lane & 15;
  const int row0 = blockIdx.x * 64;
  const int col0 = wave * 64;
  const int N = args.N;

  int arow[4];
  #pragma unroll
  for (int rt = 0; rt < 4; ++rt) { int r = row0 + rt*16 + m; arow[rt] = r < N ? r : N-1; }
  int bcol[4];
  #pragma unroll
  for (int ct = 0; ct < 4; ++ct) bcol[ct] = col0 + ct*16 + m;

  f4 osum[4][4];
  #pragma unroll
  for (int a = 0; a < 4; ++a)
    #pragma unroll
    for (int c = 0; c < 4; ++c) osum[a][c] = (f4){0.f,0.f,0.f,0.f};

  for (int t = 0; t < args.ntypes; ++t) {
    const void* Ap = args.p[t].A;
    const unsigned short* Wl = args.p[t].Wl;
    const unsigned short* Wr = args.p[t].Wr;
    const float* inv = args.p[t].invdeg;

    f4 acc[4][4];
    #pragma unroll
    for (int a = 0; a < 4; ++a)
      #pragma unroll
      for (int c = 0; c < 4; ++c) acc[a][c] = (f4){0.f,0.f,0.f,0.f};

    float scv[4];
    if (inv) {
      #pragma unroll
      for (int rt = 0; rt < 4; ++rt) scv[rt] = inv[arow[rt]];
    }

    // K-block 1: aggregated neighbor features @ Wl
    #pragma unroll
    for (int ks = 0; ks < 8; ++ks) {
      const int ko = ks*32 + q*8;
      bf8 af[4], bfr[4];
      if (inv) {
        #pragma unroll
        for (int rt = 0; rt < 4; ++rt) {
          const float* ap = (const float*)Ap + (long)arow[rt]*256 + ko;
          f4 v0 = *(const f4*)ap;
          f4 v1 = *(const f4*)(ap + 4);
          float s = scv[rt];
          bf8 a;
          a[0] = (__bf16)(v0[0]*s); a[1] = (__bf16)(v0[1]*s);
          a[2] = (__bf16)(v0[2]*s); a[3] = (__bf16)(v0[3]*s);
          a[4] = (__bf16)(v1[0]*s); a[5] = (__bf16)(v1[1]*s);
          a[6] = (__bf16)(v1[2]*s); a[7] = (__bf16)(v1[3]*s);
          af[rt] = a;
        }
      } else {
        #pragma unroll
        for (int rt = 0; rt < 4; ++rt)
          af[rt] = *(const bf8*)((const unsigned short*)Ap + (long)arow[rt]*256 + ko);
      }
      #pragma unroll
      for (int ct = 0; ct < 4; ++ct) bfr[ct] = *(const bf8*)(Wl + (long)bcol[ct]*256 + ko);
      #pragma unroll
      for (int rt = 0; rt < 4; ++rt)
        #pragma unroll
        for (int ct = 0; ct < 4; ++ct)
          acc[rt][ct] = __builtin_amdgcn_mfma_f32_16x16x32_bf16(af[rt], bfr[ct], acc[rt][ct], 0, 0, 0);
    }

    // K-block 2: x_dst @ Wr
    #pragma unroll
    for (int ks = 0; ks < 8; ++ks) {
      const int ko = ks*32 + q*8;
      bf8 af[4], bfr[4];
      #pragma unroll
      for (int rt = 0; rt < 4; ++rt)
        af[rt] = *(const bf8*)(args.xd + (long)arow[rt]*256 + ko);
      #pragma unroll
      for (int ct = 0; ct < 4; ++ct) bfr[ct] = *(const bf8*)(Wr + (long)bcol[ct]*256 + ko);
      #pragma unroll
      for (int rt = 0; rt < 4; ++rt)
        #pragma unroll
        for (int ct = 0; ct < 4; ++ct)
          acc[rt][ct] = __builtin_amdgcn_mfma_f32_16x16x32_bf16(af[rt], bfr[ct], acc[rt][ct], 0, 0, 0);
    }

    // bias
    float bv[4];
    #pragma unroll
    for (int ct = 0; ct < 4; ++ct) bv[ct] = args.p[t].bias[bcol[ct]];
    #pragma unroll
    for (int rt = 0; rt < 4; ++rt)
      #pragma unroll
      for (int ct = 0; ct < 4; ++ct)
        #pragma unroll
        for (int i = 0; i < 4; ++i) acc[rt][ct][i] += bv[ct];

    // row L2 norm across full 256 cols (4 waves)
    if (tid < 64) ssq[tid] = 0.f;
    __syncthreads();
    #pragma unroll
    for (int rt = 0; rt < 4; ++rt)
      #pragma unroll
      for (int i = 0; i < 4; ++i) {
        float p = 0.f;
        #pragma unroll
        for (int ct = 0; ct < 4; ++ct) p += acc[rt][ct][i]*acc[rt][ct][i];
        p += __shfl_xor(p, 1);
        p += __shfl_xor(p, 2);
        p += __shfl_xor(p, 4);
        p += __shfl_xor(p, 8);
        if (m == 0) atomicAdd(&ssq[rt*16 + q*4 + i], p);
      }
    __syncthreads();
    #pragma unroll
    for (int rt = 0; rt < 4; ++rt)
      #pragma unroll
      for (int i = 0; i < 4; ++i) {
        float rsc = 1.0f / fmaxf(sqrtf(ssq[rt*16 + q*4 + i]), 1e-12f);
        #pragma unroll
        for (int ct = 0; ct < 4; ++ct) osum[rt][ct][i] += acc[rt][ct][i] * rsc;
      }
    __syncthreads();
  }

  // relu + bf16 write (in place)
  #pragma unroll
  for (int rt = 0; rt < 4; ++rt)
    #pragma unroll
    for (int i = 0; i < 4; ++i) {
      int row = row0 + rt*16 + q*4 + i;
      if (row < N) {
        #pragma unroll
        for (int ct = 0; ct < 4; ++ct)
          args.out[(long)row*256 + bcol[ct]] = f2b(fmaxf(osum[rt][ct][i], 0.f));
      }
    }
}

// ---- final projection: out[NR,128] = x_reaction @ W_out + b_out (fp32 out)
__global__ __launch_bounds__(256) void k_out_gemm(
    const unsigned short* __restrict__ A, const unsigned short* __restrict__ Bt,
    const float* __restrict__ bout, float* __restrict__ out, int N)
{
  const int tid = threadIdx.x;
  const int wave = tid >> 6, lane = tid & 63;
  const int q = lane >> 4, m = lane & 15;
  const int rowblk = wave >> 1, colblk = wave & 1;
  const int row0 = blockIdx.x*128 + rowblk*64;
  const int col0 = colblk*64;

  f4 acc[4][4];
  #pragma unroll
  for (int a = 0; a < 4; ++a)
    #pragma unroll
    for (int c = 0; c < 4; ++c) acc[a][c] = (f4){0.f,0.f,0.f,0.f};

  int arow[4];
  #pragma unroll
  for (int rt = 0; rt < 4; ++rt) { int r = row0 + rt*16 + m; arow[rt] = r < N ? r : N-1; }
  int bcol[4];
  #pragma unroll
  for (int ct = 0; ct < 4; ++ct) bcol[ct] = col0 + ct*16 + m;

  #pragma unroll
  for (int ks = 0; ks < 8; ++ks) {
    const int ko = ks*32 + q*8;
    bf8 af[4], bfr[4];
    #pragma unroll
    for (int rt = 0; rt < 4; ++rt) af[rt] = *(const bf8*)(A + (long)arow[rt]*256 + ko);
    #pragma unroll
    for (int ct = 0; ct < 4; ++ct) bfr[ct] = *(const bf8*)(Bt + (long)bcol[ct]*256 + ko);
    #pragma unroll
    for (int rt = 0; rt < 4; ++rt)
      #pragma unroll
      for (int ct = 0; ct < 4; ++ct)
        acc[rt][ct] = __builtin_amdgcn_mfma_f32_16x16x32_bf16(af[rt], bfr[ct], acc[rt][ct], 0, 0, 0);
  }

  float bo[4];
  #pragma unroll
  for (int ct = 0; ct < 4; ++ct) bo[ct] = bout[bcol[ct]];

  #pragma unroll
  for (int rt = 0; rt < 4; ++rt)
    #pragma unroll
    for (int i = 0; i < 4; ++i) {
      int row = row0 + rt*16 + q*4 + i;
      if (row < N) {
        #pragma unroll
        for (int ct = 0; ct < 4; ++ct)
          out[(long)row*128 + bcol[ct]] = acc[rt][ct][i] + bo[ct];
      }
    }
}

extern "C" void kernel_launch(void* const* d_in, const int* in_sizes, int n_in,
                              void* d_out, int out_size, void* d_ws, size_t ws_size,
                              hipStream_t stream)
{
  (void)n_in; (void)out_size; (void)ws_size;
  const int NR = in_sizes[0], NC = in_sizes[1], NP = in_sizes[2], NM = in_sizes[3];
  const int E  = in_sizes[13] / 2;
  const int* idx[4] = {(const int*)d_in[0], (const int*)d_in[1], (const int*)d_in[2], (const int*)d_in[3]};
  const float* tab[4] = {(const float*)d_in[4], (const float*)d_in[5], (const float*)d_in[6], (const float*)d_in[7]};
  const float* W_l  = (const float*)d_in[8];
  const float* W_r  = (const float*)d_in[9];
  const float* bArr = (const float*)d_in[10];
  const float* W_out = (const float*)d_in[11];
  const float* b_out = (const float*)d_in[12];
  float* outp = (float*)d_out;

  int Nn[4] = {NR, NC, NP, NM};  // 0=reaction 1=complex 2=protein 3=molecule
  // EDGE_TYPES: (p,r),(m,r),(c,r),(p,c),(m,c),(r,p),(r,m)
  const int st[7] = {2,3,1,2,3,0,0};
  const int dt[7] = {0,0,0,1,1,2,3};

  uintptr_t wp = (uintptr_t)d_ws;
  auto carve = [&](size_t bytes) -> void* {
    void* p = (void*)wp;
    wp += (bytes + 255) & ~(size_t)255;
    return p;
  };
  unsigned short* Wt_l = (unsigned short*)carve((size_t)21*65536*2);   // 2.75 MB
  unsigned short* Wt_r = (unsigned short*)carve((size_t)21*65536*2);   // 2.75 MB
  unsigned short* Wt_o = (unsigned short*)carve((size_t)128*256*2);
  unsigned short* x[4];
  for (int t=0;t<4;++t) x[t] = (unsigned short*)carve((size_t)Nn[t]*256*2); // 256 MB
  int maxN = Nn[0];
  for (int t=1;t<4;++t) if (Nn[t] > maxN) maxN = Nn[t];
  float* agg = (float*)carve((size_t)maxN*256*4);                      // 204.8 MB
  unsigned short* meanR = (unsigned short*)carve((size_t)3*NR*256*2);  // 153.6 MB
  int degoff[7]; int tot = 0;
  for (int t=0;t<7;++t){ degoff[t] = tot; tot += Nn[dt[t]]; }
  float* invdeg = (float*)carve((size_t)tot*4);                        // 3 MB

  dim3 blk(256);

  // weights -> bf16 transposed
  {
    int total = 21*65536;
    k_transpose256<<<dim3((total+255)/256), blk, 0, stream>>>(W_l, Wt_l, total);
    k_transpose256<<<dim3((total+255)/256), blk, 0, stream>>>(W_r, Wt_r, total);
    k_transpose_out<<<dim3(32768/256), blk, 0, stream>>>(W_out, Wt_o);
  }
  // degrees (layer-invariant) -> invdeg = 1/max(deg,1)
  hipMemsetAsync(invdeg, 0, (size_t)tot*4, stream);
  for (int t=0;t<7;++t){
    const int* e = (const int*)d_in[13+t];
    k_deg<<<dim3((E+255)/256), blk, 0, stream>>>(e + E, E, invdeg + degoff[t]);
  }
  k_recip<<<dim3((tot+255)/256), blk, 0, stream>>>(invdeg, tot);

  // x init: embedding gather + bf16 cvt
  for (int t=0;t<4;++t)
    k_gather2<<<dim3((Nn[t]*128+255)/256), blk, 0, stream>>>(tab[t], idx[t], x[t], Nn[t]);

  dim3 sgrid(1);
  for (int l=0;l<3;++l){
    const int wbase = l*7;
    // --- reaction means (t = 0,1,2): scatter into agg, convert to bf16 meanR slabs
    for (int t=0;t<3;++t){
      const int* e = (const int*)d_in[13+t];
      hipMemsetAsync(agg, 0, (size_t)NR*256*4, stream);
      k_scatter<<<dim3((E+3)/4), blk, 0, stream>>>(x[st[t]], e, e + E, E, agg);
      k_meancvt2<<<dim3((NR*128+255)/256), blk, 0, stream>>>(
          agg, invdeg + degoff[t], meanR + (size_t)t*NR*256, NR);
    }
    // --- complex (t = 3,4): two fp32 agg slabs, fused 2-type gemm, in-place
    {
      hipMemsetAsync(agg, 0, (size_t)2*NC*256*4, stream);
      const int* e3 = (const int*)d_in[13+3];
      const int* e4 = (const int*)d_in[13+4];
      k_scatter<<<dim3((E+3)/4), blk, 0, stream>>>(x[st[3]], e3, e3 + E, E, agg);
      k_scatter<<<dim3((E+3)/4), blk, 0, stream>>>(x[st[4]], e4, e4 + E, E, agg + (size_t)NC*256);
      SageArgs a{};
      for (int j=0;j<2;++j){
        const int t = 3+j, wi = wbase+t;
        a.p[j].A = agg + (size_t)j*NC*256;
        a.p[j].Wl = Wt_l + (size_t)wi*65536;
        a.p[j].Wr = Wt_r + (size_t)wi*65536;
        a.p[j].bias = bArr + (size_t)wi*256;
        a.p[j].invdeg = invdeg + degoff[t];
      }
      a.xd = x[1]; a.out = x[1]; a.N = NC; a.ntypes = 2;
      k_sage<<<dim3((NC+63)/64), blk, 0, stream>>>(a);
    }
    // --- protein (t=5): scatter from reaction, 1-type gemm, in-place
    {
      hipMemsetAsync(agg, 0, (size_t)NP*256*4, stream);
      const int* e5 = (const int*)d_in[13+5];
      k_scatter<<<dim3((E+3)/4), blk, 0, stream>>>(x[st[5]], e5, e5 + E, E, agg);
      SageArgs a{};
      const int wi = wbase+5;
      a.p[0].A = agg;
      a.p[0].Wl = Wt_l + (size_t)wi*65536;
      a.p[0].Wr = Wt_r + (size_t)wi*65536;
      a.p[0].bias = bArr + (size_t)wi*256;
      a.p[0].invdeg = invdeg + degoff[5];
      a.xd = x[2]; a.out = x[2]; a.N = NP; a.ntypes = 1;
      k_sage<<<dim3((NP+63)/64), blk, 0, stream>>>(a);
    }
    // --- molecule (t=6)
    {
      hipMemsetAsync(agg, 0, (size_t)NM*256*4, stream);
      const int* e6 = (const int*)d_in[13+6];
      k_scatter<<<dim3((E+3)/4), blk, 0, stream>>>(x[st[6]], e6, e6 + E, E, agg);
      SageArgs a{};
      const int wi = wbase+6;
      a.p[0].A = agg;
      a.p[0].Wl = Wt_l + (size_t)wi*65536;
      a.p[0].Wr = Wt_r + (size_t)wi*65536;
      a.p[0].bias = bArr + (size_t)wi*256;
      a.p[0].invdeg = invdeg + degoff[6];
      a.xd = x[3]; a.out = x[3]; a.N = NM; a.ntypes = 1;
      k_sage<<<dim3((NM+63)/64), blk, 0, stream>>>(a);
    }
    // --- reaction (t=0,1,2) from bf16 means, 3-type gemm, in-place
    {
      SageArgs a{};
      for (int t=0;t<3;++t){
        const int wi = wbase+t;
        a.p[t].A = meanR + (size_t)t*NR*256;
        a.p[t].Wl = Wt_l + (size_t)wi*65536;
        a.p[t].Wr = Wt_r + (size_t)wi*65536;
        a.p[t].bias = bArr + (size_t)wi*256;
        a.p[t].invdeg = nullptr;
      }
      a.xd = x[0]; a.out = x[0]; a.N = NR; a.ntypes = 3;
      k_sage<<<dim3((NR+63)/64), blk, 0, stream>>>(a);
    }
  }

  k_out_gemm<<<dim3((NR+127)/128), blk, 0, stream>>>(x[0], Wt_o, b_out, outp, NR);
}

// Round 3
// 6251.125 us; speedup vs baseline: 4.1549x; 4.1549x over previous
//
#include <hip/hip_runtime.h>
#include <stdint.h>

typedef __bf16 bf8 __attribute__((ext_vector_type(8)));
typedef float  f4  __attribute__((ext_vector_type(4)));

__device__ __forceinline__ float b2f(unsigned short u){
  union { float f; unsigned int u; } v; v.u = ((unsigned int)u) << 16; return v.f;
}
__device__ __forceinline__ unsigned short f2b(float f){
  union { float f; unsigned int u; } v; v.f = f;
  unsigned int x = v.u;
  if ((x & 0x7fffffffu) > 0x7f800000u) return (unsigned short)0x7fc0; // NaN
  return (unsigned short)((x + 0x7fffu + ((x >> 16) & 1u)) >> 16);
}

// ---- weight pre-transpose: W [nmat][256][256] fp32 (k,n) -> Wt [nmat][n=256][k=256] bf16
__global__ void k_transpose256(const float* __restrict__ W, unsigned short* __restrict__ Wt, int total){
  int i = blockIdx.x*256 + threadIdx.x;
  if (i >= total) return;
  int mat = i >> 16;
  int r = i & 0xffff;
  int k = r >> 8, n = r & 255;
  Wt[(mat << 16) | (n << 8) | k] = f2b(W[i]);
}
// W_out [256][128] fp32 -> Wt [128][256] bf16
__global__ void k_transpose_out(const float* __restrict__ W, unsigned short* __restrict__ Wt){
  int i = blockIdx.x*256 + threadIdx.x;
  if (i >= 32768) return;
  int k = i >> 7, n = i & 127;
  Wt[n*256 + k] = f2b(W[i]);
}

// ---- embedding gather + cvt to bf16 (2 elems/thread)
__global__ void k_gather2(const float* __restrict__ tab, const int* __restrict__ idx,
                          unsigned short* __restrict__ x, int n){
  int i = blockIdx.x*256 + threadIdx.x;
  if (i >= n*128) return;
  int row = i >> 7, c2 = i & 127;
  const float* p = tab + (long)idx[row]*256 + c2*2;
  float2 v = *(const float2*)p;
  ushort2 o; o.x = f2b(v.x); o.y = f2b(v.y);
  *(ushort2*)(x + (long)row*256 + c2*2) = o;
}

// ================= CSR build (once per call; edges are layer-invariant) ==========
__global__ void k_hist(const int* __restrict__ dst, int E, int* __restrict__ cnt){
  int e = blockIdx.x*256 + threadIdx.x;
  if (e < E) atomicAdd(cnt + dst[e], 1);
}
// block sums of 256-elem chunks
__global__ void k_scan1(const int* __restrict__ d, int n, int* __restrict__ partials){
  __shared__ int s[256];
  int i = blockIdx.x*256 + threadIdx.x;
  s[threadIdx.x] = (i < n) ? d[i] : 0;
  __syncthreads();
  for (int off = 128; off > 0; off >>= 1){
    if (threadIdx.x < off) s[threadIdx.x] += s[threadIdx.x + off];
    __syncthreads();
  }
  if (threadIdx.x == 0) partials[blockIdx.x] = s[0];
}
// exclusive scan of partials in-place; single block of 1024 threads; nb <= 1024
__global__ void k_scan2(int* __restrict__ partials, int nb){
  __shared__ int s[1024];
  int t = threadIdx.x;
  s[t] = (t < nb) ? partials[t] : 0;
  __syncthreads();
  for (int off = 1; off < 1024; off <<= 1){
    int v = (t >= off) ? s[t - off] : 0;
    __syncthreads();
    s[t] += v;
    __syncthreads();
  }
  if (t < nb) partials[t] = (t == 0) ? 0 : s[t - 1];
}
// rowptr[i] = exclusive scan; rowptr[n] = E
__global__ void k_scan3(const int* __restrict__ d, const int* __restrict__ partials,
                        int n, int E, int* __restrict__ rowptr){
  __shared__ int s[256];
  int i = blockIdx.x*256 + threadIdx.x;
  int v = (i < n) ? d[i] : 0;
  s[threadIdx.x] = v;
  __syncthreads();
  for (int off = 1; off < 256; off <<= 1){
    int u = (threadIdx.x >= off) ? s[threadIdx.x - off] : 0;
    __syncthreads();
    s[threadIdx.x] += u;
    __syncthreads();
  }
  if (i < n) rowptr[i] = partials[blockIdx.x] + s[threadIdx.x] - v;
  if (i == 0) rowptr[n] = E;
}
__global__ void k_fill(const int* __restrict__ src, const int* __restrict__ dst, int E,
                       const int* __restrict__ rowptr, int* __restrict__ cursor,
                       int* __restrict__ col){
  int e = blockIdx.x*256 + threadIdx.x;
  if (e >= E) return;
  int d = dst[e];
  int pos = atomicAdd(cursor + d, 1);
  col[rowptr[d] + pos] = src[e];
}

// ---- CSR mean-aggregate: one wave per dst row; write bf16 mean directly
__global__ __launch_bounds__(256) void k_aggcsr(const unsigned short* __restrict__ x,
    const int* __restrict__ rowptr, const int* __restrict__ col,
    unsigned short* __restrict__ mean, int N){
  int wid = (blockIdx.x*256 + threadIdx.x) >> 6;
  if (wid >= N) return;
  int lane = threadIdx.x & 63;
  int beg = rowptr[wid], end = rowptr[wid + 1];
  float a0 = 0.f, a1 = 0.f, a2 = 0.f, a3 = 0.f;
  for (int j = beg; j < end; ++j){
    int s = col[j];
    ushort4 v = *(const ushort4*)(x + (long)s*256 + lane*4);
    a0 += b2f(v.x); a1 += b2f(v.y); a2 += b2f(v.z); a3 += b2f(v.w);
  }
  int deg = end - beg;
  float inv = 1.0f / (float)(deg > 1 ? deg : 1);
  ushort4 o;
  o.x = f2b(a0*inv); o.y = f2b(a1*inv); o.z = f2b(a2*inv); o.w = f2b(a3*inv);
  *(ushort4*)(mean + (long)wid*256 + lane*4) = o;
}

// ---- fused multi-type SAGE layer kernel
// x_d_new = relu( sum_t normalize(mean_t@Wl_t + x_d@Wr_t + b_t) ), in-place safe:
// each block reads only its own 64 rows of xd.
struct SagePart {
  const unsigned short* A;       // [N][256] bf16 mean
  const unsigned short* Wl;      // [n=256][k=256] bf16
  const unsigned short* Wr;      // [n=256][k=256] bf16
  const float* bias;             // [256] fp32
};
struct SageArgs {
  SagePart p[3];
  const unsigned short* xd;      // [N][256] bf16
  unsigned short* out;           // [N][256] bf16 (aliases xd)
  int N;
  int ntypes;
};

__global__ __launch_bounds__(256) void k_sage(SageArgs args)
{
  __shared__ float ssq[64];
  const int tid = threadIdx.x;
  const int wave = tid >> 6, lane = tid & 63;
  const int q = lane >> 4, m = lane & 15;
  const int row0 = blockIdx.x * 64;
  const int col0 = wave * 64;
  const int N = args.N;

  int arow[4];
  #pragma unroll
  for (int rt = 0; rt < 4; ++rt) { int r = row0 + rt*16 + m; arow[rt] = r < N ? r : N-1; }
  int bcol[4];
  #pragma unroll
  for (int ct = 0; ct < 4; ++ct) bcol[ct] = col0 + ct*16 + m;

  f4 osum[4][4];
  #pragma unroll
  for (int a = 0; a < 4; ++a)
    #pragma unroll
    for (int c = 0; c < 4; ++c) osum[a][c] = (f4){0.f,0.f,0.f,0.f};

  for (int t = 0; t < args.ntypes; ++t) {
    const unsigned short* Ap = args.p[t].A;
    const unsigned short* Wl = args.p[t].Wl;
    const unsigned short* Wr = args.p[t].Wr;

    f4 acc[4][4];
    #pragma unroll
    for (int a = 0; a < 4; ++a)
      #pragma unroll
      for (int c = 0; c < 4; ++c) acc[a][c] = (f4){0.f,0.f,0.f,0.f};

    // K-block 1: mean @ Wl
    #pragma unroll
    for (int ks = 0; ks < 8; ++ks) {
      const int ko = ks*32 + q*8;
      bf8 af[4], bfr[4];
      #pragma unroll
      for (int rt = 0; rt < 4; ++rt)
        af[rt] = *(const bf8*)(Ap + (long)arow[rt]*256 + ko);
      #pragma unroll
      for (int ct = 0; ct < 4; ++ct) bfr[ct] = *(const bf8*)(Wl + (long)bcol[ct]*256 + ko);
      #pragma unroll
      for (int rt = 0; rt < 4; ++rt)
        #pragma unroll
        for (int ct = 0; ct < 4; ++ct)
          acc[rt][ct] = __builtin_amdgcn_mfma_f32_16x16x32_bf16(af[rt], bfr[ct], acc[rt][ct], 0, 0, 0);
    }
    // K-block 2: x_dst @ Wr
    #pragma unroll
    for (int ks = 0; ks < 8; ++ks) {
      const int ko = ks*32 + q*8;
      bf8 af[4], bfr[4];
      #pragma unroll
      for (int rt = 0; rt < 4; ++rt)
        af[rt] = *(const bf8*)(args.xd + (long)arow[rt]*256 + ko);
      #pragma unroll
      for (int ct = 0; ct < 4; ++ct) bfr[ct] = *(const bf8*)(Wr + (long)bcol[ct]*256 + ko);
      #pragma unroll
      for (int rt = 0; rt < 4; ++rt)
        #pragma unroll
        for (int ct = 0; ct < 4; ++ct)
          acc[rt][ct] = __builtin_amdgcn_mfma_f32_16x16x32_bf16(af[rt], bfr[ct], acc[rt][ct], 0, 0, 0);
    }

    // bias
    float bv[4];
    #pragma unroll
    for (int ct = 0; ct < 4; ++ct) bv[ct] = args.p[t].bias[bcol[ct]];
    #pragma unroll
    for (int rt = 0; rt < 4; ++rt)
      #pragma unroll
      for (int ct = 0; ct < 4; ++ct)
        #pragma unroll
        for (int i = 0; i < 4; ++i) acc[rt][ct][i] += bv[ct];

    // row L2 norm across full 256 cols (4 waves)
    if (tid < 64) ssq[tid] = 0.f;
    __syncthreads();
    #pragma unroll
    for (int rt = 0; rt < 4; ++rt)
      #pragma unroll
      for (int i = 0; i < 4; ++i) {
        float p = 0.f;
        #pragma unroll
        for (int ct = 0; ct < 4; ++ct) p += acc[rt][ct][i]*acc[rt][ct][i];
        p += __shfl_xor(p, 1);
        p += __shfl_xor(p, 2);
        p += __shfl_xor(p, 4);
        p += __shfl_xor(p, 8);
        if (m == 0) atomicAdd(&ssq[rt*16 + q*4 + i], p);
      }
    __syncthreads();
    #pragma unroll
    for (int rt = 0; rt < 4; ++rt)
      #pragma unroll
      for (int i = 0; i < 4; ++i) {
        float rsc = 1.0f / fmaxf(sqrtf(ssq[rt*16 + q*4 + i]), 1e-12f);
        #pragma unroll
        for (int ct = 0; ct < 4; ++ct) osum[rt][ct][i] += acc[rt][ct][i] * rsc;
      }
    __syncthreads();
  }

  // relu + bf16 write (in place)
  #pragma unroll
  for (int rt = 0; rt < 4; ++rt)
    #pragma unroll
    for (int i = 0; i < 4; ++i) {
      int row = row0 + rt*16 + q*4 + i;
      if (row < N) {
        #pragma unroll
        for (int ct = 0; ct < 4; ++ct)
          args.out[(long)row*256 + bcol[ct]] = f2b(fmaxf(osum[rt][ct][i], 0.f));
      }
    }
}

// ---- final projection: out[NR,128] = x_reaction @ W_out + b_out (fp32 out)
__global__ __launch_bounds__(256) void k_out_gemm(
    const unsigned short* __restrict__ A, const unsigned short* __restrict__ Bt,
    const float* __restrict__ bout, float* __restrict__ out, int N)
{
  const int tid = threadIdx.x;
  const int wave = tid >> 6, lane = tid & 63;
  const int q = lane >> 4, m = lane & 15;
  const int rowblk = wave >> 1, colblk = wave & 1;
  const int row0 = blockIdx.x*128 + rowblk*64;
  const int col0 = colblk*64;

  f4 acc[4][4];
  #pragma unroll
  for (int a = 0; a < 4; ++a)
    #pragma unroll
    for (int c = 0; c < 4; ++c) acc[a][c] = (f4){0.f,0.f,0.f,0.f};

  int arow[4];
  #pragma unroll
  for (int rt = 0; rt < 4; ++rt) { int r = row0 + rt*16 + m; arow[rt] = r < N ? r : N-1; }
  int bcol[4];
  #pragma unroll
  for (int ct = 0; ct < 4; ++ct) bcol[ct] = col0 + ct*16 + m;

  #pragma unroll
  for (int ks = 0; ks < 8; ++ks) {
    const int ko = ks*32 + q*8;
    bf8 af[4], bfr[4];
    #pragma unroll
    for (int rt = 0; rt < 4; ++rt) af[rt] = *(const bf8*)(A + (long)arow[rt]*256 + ko);
    #pragma unroll
    for (int ct = 0; ct < 4; ++ct) bfr[ct] = *(const bf8*)(Bt + (long)bcol[ct]*256 + ko);
    #pragma unroll
    for (int rt = 0; rt < 4; ++rt)
      #pragma unroll
      for (int ct = 0; ct < 4; ++ct)
        acc[rt][ct] = __builtin_amdgcn_mfma_f32_16x16x32_bf16(af[rt], bfr[ct], acc[rt][ct], 0, 0, 0);
  }

  float bo[4];
  #pragma unroll
  for (int ct = 0; ct < 4; ++ct) bo[ct] = bout[bcol[ct]];

  #pragma unroll
  for (int rt = 0; rt < 4; ++rt)
    #pragma unroll
    for (int i = 0; i < 4; ++i) {
      int row = row0 + rt*16 + q*4 + i;
      if (row < N) {
        #pragma unroll
        for (int ct = 0; ct < 4; ++ct)
          out[(long)row*128 + bcol[ct]] = acc[rt][ct][i] + bo[ct];
      }
    }
}

extern "C" void kernel_launch(void* const* d_in, const int* in_sizes, int n_in,
                              void* d_out, int out_size, void* d_ws, size_t ws_size,
                              hipStream_t stream)
{
  (void)n_in; (void)out_size; (void)ws_size;
  const int NR = in_sizes[0], NC = in_sizes[1], NP = in_sizes[2], NM = in_sizes[3];
  const int E  = in_sizes[13] / 2;
  const int* idx[4] = {(const int*)d_in[0], (const int*)d_in[1], (const int*)d_in[2], (const int*)d_in[3]};
  const float* tab[4] = {(const float*)d_in[4], (const float*)d_in[5], (const float*)d_in[6], (const float*)d_in[7]};
  const float* W_l  = (const float*)d_in[8];
  const float* W_r  = (const float*)d_in[9];
  const float* bArr = (const float*)d_in[10];
  const float* W_out = (const float*)d_in[11];
  const float* b_out = (const float*)d_in[12];
  float* outp = (float*)d_out;

  int Nn[4] = {NR, NC, NP, NM};  // 0=reaction 1=complex 2=protein 3=molecule
  // EDGE_TYPES: (p,r),(m,r),(c,r),(p,c),(m,c),(r,p),(r,m)
  const int st[7] = {2,3,1,2,3,0,0};
  const int dt[7] = {0,0,0,1,1,2,3};

  uintptr_t wp = (uintptr_t)d_ws;
  auto carve = [&](size_t bytes) -> void* {
    void* p = (void*)wp;
    wp += (bytes + 255) & ~(size_t)255;
    return p;
  };
  unsigned short* Wt_l = (unsigned short*)carve((size_t)21*65536*2);   // 2.75 MB
  unsigned short* Wt_r = (unsigned short*)carve((size_t)21*65536*2);   // 2.75 MB
  unsigned short* Wt_o = (unsigned short*)carve((size_t)128*256*2);
  unsigned short* x[4];
  for (int t=0;t<4;++t) x[t] = (unsigned short*)carve((size_t)Nn[t]*256*2); // 256 MB
  unsigned short* meanR = (unsigned short*)carve((size_t)3*NR*256*2);  // 153.6 MB
  int maxN = Nn[0];
  for (int t=1;t<4;++t) if (Nn[t] > maxN) maxN = Nn[t];
  int arenaRows = maxN > 2*NC ? maxN : 2*NC;
  unsigned short* arena = (unsigned short*)carve((size_t)arenaRows*256*2); // 102.4 MB
  int* rowptr[7];
  for (int t=0;t<7;++t) rowptr[t] = (int*)carve((size_t)(Nn[dt[t]]+1)*4);  // ~3 MB
  int* col[7];
  for (int t=0;t<7;++t) col[t] = (int*)carve((size_t)E*4);                 // 8.4 MB
  int* cnt = (int*)carve((size_t)maxN*4);                                  // 0.8 MB
  int* partials = (int*)carve((size_t)1024*4);

  dim3 blk(256);

  // weights -> bf16 transposed
  {
    int total = 21*65536;
    k_transpose256<<<dim3((total+255)/256), blk, 0, stream>>>(W_l, Wt_l, total);
    k_transpose256<<<dim3((total+255)/256), blk, 0, stream>>>(W_r, Wt_r, total);
    k_transpose_out<<<dim3(32768/256), blk, 0, stream>>>(W_out, Wt_o);
  }

  // x init: embedding gather + bf16 cvt
  for (int t=0;t<4;++t)
    k_gather2<<<dim3((Nn[t]*128+255)/256), blk, 0, stream>>>(tab[t], idx[t], x[t], Nn[t]);

  // ---- CSR build (once; edges are constant across layers)
  for (int t=0;t<7;++t){
    const int* e = (const int*)d_in[13+t];
    const int Nd = Nn[dt[t]];
    const int nb = (Nd + 255) / 256;
    hipMemsetAsync(cnt, 0, (size_t)Nd*4, stream);
    k_hist<<<dim3((E+255)/256), blk, 0, stream>>>(e + E, E, cnt);
    k_scan1<<<dim3(nb), blk, 0, stream>>>(cnt, Nd, partials);
    k_scan2<<<dim3(1), dim3(1024), 0, stream>>>(partials, nb);
    k_scan3<<<dim3(nb), blk, 0, stream>>>(cnt, partials, Nd, E, rowptr[t]);
    hipMemsetAsync(cnt, 0, (size_t)Nd*4, stream);
    k_fill<<<dim3((E+255)/256), blk, 0, stream>>>(e, e + E, E, rowptr[t], cnt, col[t]);
  }

  for (int l=0;l<3;++l){
    const int wbase = l*7;
    // reaction means (t=0,1,2) into dedicated slabs (consumed last)
    for (int t=0;t<3;++t)
      k_aggcsr<<<dim3((NR+3)/4), blk, 0, stream>>>(
          x[st[t]], rowptr[t], col[t], meanR + (size_t)t*NR*256, NR);
    // complex (t=3,4) -> arena slabs, fused 2-type gemm, in-place
    {
      k_aggcsr<<<dim3((NC+3)/4), blk, 0, stream>>>(x[st[3]], rowptr[3], col[3], arena, NC);
      k_aggcsr<<<dim3((NC+3)/4), blk, 0, stream>>>(x[st[4]], rowptr[4], col[4], arena + (size_t)NC*256, NC);
      SageArgs a{};
      for (int j=0;j<2;++j){
        const int wi = wbase+3+j;
        a.p[j].A = arena + (size_t)j*NC*256;
        a.p[j].Wl = Wt_l + (size_t)wi*65536;
        a.p[j].Wr = Wt_r + (size_t)wi*65536;
        a.p[j].bias = bArr + (size_t)wi*256;
      }
      a.xd = x[1]; a.out = x[1]; a.N = NC; a.ntypes = 2;
      k_sage<<<dim3((NC+63)/64), blk, 0, stream>>>(a);
    }
    // protein (t=5): sources reaction (not yet updated)
    {
      k_aggcsr<<<dim3((NP+3)/4), blk, 0, stream>>>(x[st[5]], rowptr[5], col[5], arena, NP);
      SageArgs a{};
      const int wi = wbase+5;
      a.p[0].A = arena;
      a.p[0].Wl = Wt_l + (size_t)wi*65536;
      a.p[0].Wr = Wt_r + (size_t)wi*65536;
      a.p[0].bias = bArr + (size_t)wi*256;
      a.xd = x[2]; a.out = x[2]; a.N = NP; a.ntypes = 1;
      k_sage<<<dim3((NP+63)/64), blk, 0, stream>>>(a);
    }
    // molecule (t=6): sources reaction (not yet updated)
    {
      k_aggcsr<<<dim3((NM+3)/4), blk, 0, stream>>>(x[st[6]], rowptr[6], col[6], arena, NM);
      SageArgs a{};
      const int wi = wbase+6;
      a.p[0].A = arena;
      a.p[0].Wl = Wt_l + (size_t)wi*65536;
      a.p[0].Wr = Wt_r + (size_t)wi*65536;
      a.p[0].bias = bArr + (size_t)wi*256;
      a.xd = x[3]; a.out = x[3]; a.N = NM; a.ntypes = 1;
      k_sage<<<dim3((NM+63)/64), blk, 0, stream>>>(a);
    }
    // reaction (t=0,1,2) from saved means, 3-type gemm, in-place (last)
    {
      SageArgs a{};
      for (int t=0;t<3;++t){
        const int wi = wbase+t;
        a.p[t].A = meanR + (size_t)t*NR*256;
        a.p[t].Wl = Wt_l + (size_t)wi*65536;
        a.p[t].Wr = Wt_r + (size_t)wi*65536;
        a.p[t].bias = bArr + (size_t)wi*256;
      }
      a.xd = x[0]; a.out = x[0]; a.N = NR; a.ntypes = 3;
      k_sage<<<dim3((NR+63)/64), blk, 0, stream>>>(a);
    }
  }

  k_out_gemm<<<dim3((NR+127)/128), blk, 0, stream>>>(x[0], Wt_o, b_out, outp, NR);
}